// Round 10
// baseline (66.957 us; speedup 1.0000x reference)
//
#include <hip/hip_runtime.h>

// Problem constants (match reference)
#define B_  16
#define P_  32
#define L_  512
#define M_  32
#define LE_ 2048

#define MGRP 4                   // m-rows per staging group
#define NGRP (M_ / MGRP)         // 8 groups

// One block per (b,p) row, 512 threads, all 32 m's.
//  - search once per query (4/thread), results in registers
//  - m processed in 8 groups of 4; params double-buffered in LDS (2x24KB)
//  - T14 pipeline: issue group g+1 global loads -> compute group g from LDS
//    -> ds_write prefetch into other buffer -> one __syncthreads per group
// Numerics (validated r6/r7): qn = q * fl32_CR(1/nc); side='left'
// lower_bound + end-correction; dt = qn - t_last; __expf; scale inv_nc.
__global__ __launch_bounds__(512) void hawkes_fused_pipe(
    const float* __restrict__ q,      // [B,P,LE]
    const float* __restrict__ ev,     // [B,P,L]
    const float* __restrict__ mu,     // [B,M,P,L]
    const float* __restrict__ alpha,  // [B,M,P,L]
    const float* __restrict__ beta,   // [B,M,P,L]
    const float* __restrict__ nc,     // [B]
    float* __restrict__ out)          // [B,M,P,LE]
{
    __shared__ float sev[L_];                      // 2 KB
    __shared__ float sbuf[2][3][MGRP][L_];         // 2 x 24 KB (mu/al/be)

    const int row = blockIdx.x;                    // b*P_ + p
    const int b   = row / P_;
    const int p   = row % P_;
    const int tid = threadIdx.x;                   // 0..511

    // ---- stage event row (512 floats, one per thread) ----
    const float* evrow = ev + (size_t)row * L_;
    sev[tid] = evrow[tid];

    const float* parr[3] = { mu, alpha, beta };
    const size_t pbase   = (((size_t)b * M_) * P_ + p) * L_;  // m=0 row
    const size_t mstride = (size_t)P_ * L_;                   // m stride (floats)

    // per-thread staging slot: row r0 = tid/128, float offset l40 = (tid%128)*4
    const int r0  = tid >> 7;
    const int l40 = (tid & 127) << 2;

    // ---- prologue: stage group 0 ----
    float4 pre[3];
    #pragma unroll
    for (int a = 0; a < 3; ++a) {
        const float* src = parr[a] + pbase + (size_t)r0 * mstride + l40;
        pre[a] = *(const float4*)src;
    }
    #pragma unroll
    for (int a = 0; a < 3; ++a)
        *(float4*)&sbuf[0][a][r0][l40] = pre[a];
    __syncthreads();

    // ---- search: 4 queries per thread, once per block ----
    const float inv_nc = (float)(1.0 / (double)nc[b]);  // CR f32 reciprocal
    const float4 qv = *(const float4*)(q + (size_t)row * LE_ + 4 * tid);

    int   idx[4];
    float dt[4];
    #pragma unroll
    for (int i = 0; i < 4; ++i) {
        const float qn = ((const float*)&qv)[i] * inv_nc;
        int pos = 0;
        #pragma unroll
        for (int half = 256; half >= 1; half >>= 1) {
            const int cand = pos + half;
            pos = (sev[cand - 1] < qn) ? cand : pos;
        }
        pos += (sev[pos] < qn) ? 1 : 0;    // extend range to 512
        const int last = pos - 1;
        idx[i] = (last < 0) ? 0 : last;
        const float tl = (last < 0) ? 0.0f : sev[idx[i]];
        dt[i] = qn - tl;
    }

    const size_t ostride = (size_t)P_ * LE_;           // m stride in out
    const size_t obase0  = (((size_t)b * M_) * P_ + p) * LE_ + 4 * tid;

    // ---- main loop: 8 m-groups, double-buffered ----
    #pragma unroll
    for (int g = 0; g < NGRP; ++g) {
        const int cur = g & 1;

        // issue next group's loads (latency hides under compute)
        if (g < NGRP - 1) {
            #pragma unroll
            for (int a = 0; a < 3; ++a) {
                const float* src = parr[a] + pbase
                                 + (size_t)((g + 1) * MGRP + r0) * mstride + l40;
                pre[a] = *(const float4*)src;
            }
        }

        // compute rows m = g*MGRP .. g*MGRP+3
        #pragma unroll
        for (int mr = 0; mr < MGRP; ++mr) {
            float4 o;
            #pragma unroll
            for (int i = 0; i < 4; ++i) {
                const float mul = sbuf[cur][0][mr][idx[i]];
                const float al  = sbuf[cur][1][mr][idx[i]];
                const float be  = sbuf[cur][2][mr][idx[i]];
                ((float*)&o)[i] = (mul + (al - mul) * __expf(-be * dt[i])) * inv_nc;
            }
            *(float4*)(out + obase0 + (size_t)(g * MGRP + mr) * ostride) = o;
        }

        // park prefetch into the other buffer (disjoint from buffer being read)
        if (g < NGRP - 1) {
            #pragma unroll
            for (int a = 0; a < 3; ++a)
                *(float4*)&sbuf[cur ^ 1][a][r0][l40] = pre[a];
        }
        __syncthreads();   // write-visibility for next group; keeps waves in step
    }
}

extern "C" void kernel_launch(void* const* d_in, const int* in_sizes, int n_in,
                              void* d_out, int out_size, void* d_ws, size_t ws_size,
                              hipStream_t stream) {
    const float* q     = (const float*)d_in[0];  // query_times [B,P,LE]
    const float* ev    = (const float*)d_in[1];  // event_times [B,P,L]
    const float* mu    = (const float*)d_in[2];  // [B,M,P,L]
    const float* alpha = (const float*)d_in[3];  // [B,M,P,L]
    const float* beta  = (const float*)d_in[4];  // [B,M,P,L]
    const float* nc    = (const float*)d_in[5];  // [B]
    float* out = (float*)d_out;                  // [B,M,P,LE]

    dim3 grid(B_ * P_);                          // 512 blocks (one per row)
    dim3 block(512);
    hipLaunchKernelGGL(hawkes_fused_pipe, grid, block, 0, stream,
                       q, ev, mu, alpha, beta, nc, out);
}

// Round 11
// 50.939 us; speedup vs baseline: 1.3144x; 1.3144x over previous
//
#include <hip/hip_runtime.h>

// Problem constants (match reference)
#define B_  16
#define P_  32
#define L_  512
#define M_  32
#define LE_ 2048

#define MSPLIT 8                 // m's per block
#define MC     (M_ / MSPLIT)     // 4 m-groups

// Round-7 kernel + XCD-aware block swizzle (T1).
// The 4 sibling blocks of one (b,p) row (mc=0..3) share a 50KB param set +
// 8KB q row; default dispatch round-robins consecutive bids across the 8
// XCDs, so siblings fetch the same bytes through 4 different L2s. Remap:
//   x = bid&7 (XCD), k = bid>>3, mc = k&3, row = x + 8*(k>>2)
// -> all 4 siblings have bid ≡ x (mod 8) (same XCD) and consecutive k
// (dispatched together) -> 3 of 4 param reads become L2 hits, cutting
// memory-side read traffic ~4x. Numerics identical to validated r6/r7:
// qn = q * fl32_CR(1/nc); side='left' lower_bound + end-correction;
// dt = qn - t_last; __expf; scale inv_nc.
__global__ __launch_bounds__(256) void hawkes_intensity_kernel(
    const float* __restrict__ q,      // [B,P,LE]
    const float* __restrict__ ev,     // [B,P,L]
    const float* __restrict__ mu,     // [B,M,P,L]
    const float* __restrict__ alpha,  // [B,M,P,L]
    const float* __restrict__ beta,   // [B,M,P,L]
    const float* __restrict__ nc,     // [B]
    float* __restrict__ out)          // [B,M,P,LE]
{
    __shared__ float sev[L_];
    __shared__ float smu[MSPLIT][L_];
    __shared__ float sal[MSPLIT][L_];
    __shared__ float sbe[MSPLIT][L_];

    // XCD-aware swizzle: siblings (same row, mc=0..3) on the same XCD.
    const int bid = blockIdx.x;
    const int x   = bid & 7;                 // XCD (dispatch round-robins %8)
    const int k   = bid >> 3;                // slot within XCD
    const int mc  = k & (MC - 1);            // m-group
    const int row = x + 8 * (k >> 2);        // b*P_ + p  (bijective over 512)

    const int b   = row / P_;
    const int p   = row % P_;
    const int m0  = mc * MSPLIT;
    const int tid = threadIdx.x;

    // Stage event row (512 floats)
    const float* evrow = ev + (size_t)row * L_;
    sev[tid]       = evrow[tid];
    sev[tid + 256] = evrow[tid + 256];

    // Stage params: 8 m-rows per array, 512 floats each = 1024 float4s/array.
    const size_t pbase   = (((size_t)b * M_ + m0) * P_ + p) * L_;
    const size_t mstride = (size_t)P_ * L_;  // 16384 floats between m rows
    #pragma unroll
    for (int i = 0; i < 4; ++i) {
        const int fidx = tid + 256 * i;      // 0..1023
        const int ml   = fidx >> 7;          // /128
        const int l4   = (fidx & 127) << 2;  // float offset in row
        const size_t g = pbase + (size_t)ml * mstride + l4;
        *(float4*)&smu[ml][l4] = *(const float4*)(mu    + g);
        *(float4*)&sal[ml][l4] = *(const float4*)(alpha + g);
        *(float4*)&sbe[ml][l4] = *(const float4*)(beta  + g);
    }
    __syncthreads();

    const float ncv    = nc[b];
    const float inv_nc = (float)(1.0 / (double)ncv);  // CR f32 reciprocal
    const float* qrow  = q + (size_t)row * LE_;

    #pragma unroll
    for (int pass = 0; pass < 2; ++pass) {
        const int le0 = 1024 * pass + 4 * tid;
        const float4 qv = *(const float4*)(qrow + le0);

        int   idx[4];
        float dt[4];
        #pragma unroll
        for (int i = 0; i < 4; ++i) {
            const float qn = ((const float*)&qv)[i] * inv_nc;
            int pos = 0;
            #pragma unroll
            for (int half = 256; half >= 1; half >>= 1) {
                const int cand = pos + half;
                pos = (sev[cand - 1] < qn) ? cand : pos;
            }
            pos += (sev[pos] < qn) ? 1 : 0;   // extend range to 512
            const int last = pos - 1;
            idx[i] = (last < 0) ? 0 : last;
            const float tl = (last < 0) ? 0.0f : sev[idx[i]];
            dt[i] = qn - tl;
        }

        const size_t obase = (((size_t)b * M_ + m0) * P_ + p) * LE_ + le0;
        #pragma unroll
        for (int m = 0; m < MSPLIT; ++m) {
            float4 o;
            #pragma unroll
            for (int i = 0; i < 4; ++i) {
                const float mul = smu[m][idx[i]];
                const float al  = sal[m][idx[i]];
                const float be  = sbe[m][idx[i]];
                ((float*)&o)[i] = (mul + (al - mul) * __expf(-be * dt[i])) * inv_nc;
            }
            *(float4*)(out + obase + (size_t)m * ((size_t)P_ * LE_)) = o;
        }
    }
}

extern "C" void kernel_launch(void* const* d_in, const int* in_sizes, int n_in,
                              void* d_out, int out_size, void* d_ws, size_t ws_size,
                              hipStream_t stream) {
    const float* q     = (const float*)d_in[0];  // query_times [B,P,LE]
    const float* ev    = (const float*)d_in[1];  // event_times [B,P,L]
    const float* mu    = (const float*)d_in[2];  // [B,M,P,L]
    const float* alpha = (const float*)d_in[3];  // [B,M,P,L]
    const float* beta  = (const float*)d_in[4];  // [B,M,P,L]
    const float* nc    = (const float*)d_in[5];  // [B]
    float* out = (float*)d_out;                  // [B,M,P,LE]

    dim3 grid(B_ * P_ * MC);                     // 2048 blocks
    dim3 block(256);
    hipLaunchKernelGGL(hawkes_intensity_kernel, grid, block, 0, stream,
                       q, ev, mu, alpha, beta, nc, out);
}

// Round 12
// 47.520 us; speedup vs baseline: 1.4090x; 1.0720x over previous
//
#include <hip/hip_runtime.h>

// Problem constants (match reference)
#define B_  16
#define P_  32
#define L_  512
#define M_  32
#define LE_ 2048

#define MSPLIT 8                 // m's per block
#define MC     (M_ / MSPLIT)     // 4 m-groups

// r7 structure + two changes:
//  1) param staging via __builtin_amdgcn_global_load_lds width=16 (no
//     ds_write_b128, no staging VGPRs; vmcnt-tracked direct-to-LDS DMA)
//  2) barrier split: raw s_barrier+lgkmcnt(0) after sev staging (params
//     still in flight) -> binary search overlaps the param fetch ->
//     __syncthreads() (vmcnt(0)+lgkm(0) drain) -> gathers.
// Numerics identical to validated r6/r7: qn = q * fl32_CR(1/nc);
// side='left' lower_bound + end-correction; dt = qn - t_last; __expf;
// scale by inv_nc.

__device__ __forceinline__ void gload_lds16(const float* g, float* l) {
    __builtin_amdgcn_global_load_lds(
        (const __attribute__((address_space(1))) void*)g,
        (__attribute__((address_space(3))) void*)l, 16, 0, 0);
}

__global__ __launch_bounds__(256) void hawkes_intensity_kernel(
    const float* __restrict__ q,      // [B,P,LE]
    const float* __restrict__ ev,     // [B,P,L]
    const float* __restrict__ mu,     // [B,M,P,L]
    const float* __restrict__ alpha,  // [B,M,P,L]
    const float* __restrict__ beta,   // [B,M,P,L]
    const float* __restrict__ nc,     // [B]
    float* __restrict__ out)          // [B,M,P,LE]
{
    __shared__ float sev[L_];
    __shared__ float smu[MSPLIT][L_];
    __shared__ float sal[MSPLIT][L_];
    __shared__ float sbe[MSPLIT][L_];

    const int bid = blockIdx.x;
    const int mc  = bid & (MC - 1);          // m-group (fastest)
    const int row = bid >> 2;                // b*P_ + p
    const int b   = row / P_;
    const int p   = row % P_;
    const int m0  = mc * MSPLIT;
    const int tid = threadIdx.x;

    // ---- issue order matters: ev first (oldest vmcnt), then q, then params
    const float* evrow = ev + (size_t)row * L_;
    const float e0 = evrow[tid];
    const float e1 = evrow[tid + 256];

    const float* qrow = q + (size_t)row * LE_;
    const float4 qv0 = *(const float4*)(qrow + 4 * tid);          // pass 0
    const float4 qv1 = *(const float4*)(qrow + 1024 + 4 * tid);   // pass 1

    // stage sev (compiler waits only for the ev loads: vmcnt(N), N>0)
    sev[tid]       = e0;
    sev[tid + 256] = e1;

    // ---- issue param staging: 36 global_load_lds dwordx4, stay in flight
    const size_t pbase   = (((size_t)b * M_ + m0) * P_ + p) * L_;
    const size_t mstride = (size_t)P_ * L_;
    #pragma unroll
    for (int i = 0; i < 4; ++i) {
        const int fidx = tid + 256 * i;          // 0..1023
        const int ml   = fidx >> 7;              // wave-uniform (64 | 128)
        const int l4   = (fidx & 127) << 2;      // lane-linear, 16B steps
        const int fb   = (tid & ~63) + 256 * i;  // wave base slot
        const int l4b  = (fb & 127) << 2;
        const size_t g = pbase + (size_t)ml * mstride + l4;
        gload_lds16(mu    + g, &smu[ml][l4b]);
        gload_lds16(alpha + g, &sal[ml][l4b]);
        gload_lds16(beta  + g, &sbe[ml][l4b]);
    }

    // ---- barrier 1: sev visible; params still in flight (no vmcnt drain)
    asm volatile("s_waitcnt lgkmcnt(0)" ::: "memory");
    __builtin_amdgcn_s_barrier();
    __builtin_amdgcn_sched_barrier(0);

    const float ncv    = nc[b];
    const float inv_nc = (float)(1.0 / (double)ncv);  // CR f32 reciprocal

    // ---- search (overlaps param fetch): 8 queries/thread
    int   idx[2][4];
    float dt[2][4];
    #pragma unroll
    for (int pass = 0; pass < 2; ++pass) {
        const float4 qv = pass ? qv1 : qv0;
        #pragma unroll
        for (int i = 0; i < 4; ++i) {
            const float qn = ((const float*)&qv)[i] * inv_nc;
            int pos = 0;
            #pragma unroll
            for (int half = 256; half >= 1; half >>= 1) {
                const int cand = pos + half;
                pos = (sev[cand - 1] < qn) ? cand : pos;
            }
            pos += (sev[pos] < qn) ? 1 : 0;      // extend range to 512
            const int last = pos - 1;
            idx[pass][i] = (last < 0) ? 0 : last;
            const float tl = (last < 0) ? 0.0f : sev[idx[pass][i]];
            dt[pass][i] = qn - tl;
        }
    }

    // ---- barrier 2: __syncthreads drains vmcnt(0) -> params in LDS
    __syncthreads();

    // ---- gather + evaluate + store
    #pragma unroll
    for (int pass = 0; pass < 2; ++pass) {
        const int le0 = 1024 * pass + 4 * tid;
        const size_t obase = (((size_t)b * M_ + m0) * P_ + p) * LE_ + le0;
        #pragma unroll
        for (int m = 0; m < MSPLIT; ++m) {
            float4 o;
            #pragma unroll
            for (int i = 0; i < 4; ++i) {
                const int   ix  = idx[pass][i];
                const float mul = smu[m][ix];
                const float al  = sal[m][ix];
                const float be  = sbe[m][ix];
                ((float*)&o)[i] = (mul + (al - mul) * __expf(-be * dt[pass][i])) * inv_nc;
            }
            *(float4*)(out + obase + (size_t)m * ((size_t)P_ * LE_)) = o;
        }
    }
}

extern "C" void kernel_launch(void* const* d_in, const int* in_sizes, int n_in,
                              void* d_out, int out_size, void* d_ws, size_t ws_size,
                              hipStream_t stream) {
    const float* q     = (const float*)d_in[0];  // query_times [B,P,LE]
    const float* ev    = (const float*)d_in[1];  // event_times [B,P,L]
    const float* mu    = (const float*)d_in[2];  // [B,M,P,L]
    const float* alpha = (const float*)d_in[3];  // [B,M,P,L]
    const float* beta  = (const float*)d_in[4];  // [B,M,P,L]
    const float* nc    = (const float*)d_in[5];  // [B]
    float* out = (float*)d_out;                  // [B,M,P,LE]

    dim3 grid(B_ * P_ * MC);                     // 2048 blocks
    dim3 block(256);
    hipLaunchKernelGGL(hawkes_intensity_kernel, grid, block, 0, stream,
                       q, ev, mu, alpha, beta, nc, out);
}

// Round 13
// 43.357 us; speedup vs baseline: 1.5443x; 1.0960x over previous
//
#include <hip/hip_runtime.h>

// Problem constants (match reference)
#define B_  16
#define P_  32
#define L_  512
#define M_  32
#define LE_ 2048

#define MSPLIT 8                 // m's per block
#define MC     (M_ / MSPLIT)     // 4 m-groups

// r12 structure (gload_lds staging + split barrier) at 512 threads/block:
// 24 resident waves/CU (vs 12) for latency hiding; each thread 4 queries.
// Numerics identical to validated r6/r7: qn = q * fl32_CR(1/nc);
// side='left' lower_bound + end-correction; dt = qn - t_last; __expf;
// scale by inv_nc.

__device__ __forceinline__ void gload_lds16(const float* g, float* l) {
    __builtin_amdgcn_global_load_lds(
        (const __attribute__((address_space(1))) void*)g,
        (__attribute__((address_space(3))) void*)l, 16, 0, 0);
}

__global__ __launch_bounds__(512) void hawkes_intensity_kernel(
    const float* __restrict__ q,      // [B,P,LE]
    const float* __restrict__ ev,     // [B,P,L]
    const float* __restrict__ mu,     // [B,M,P,L]
    const float* __restrict__ alpha,  // [B,M,P,L]
    const float* __restrict__ beta,   // [B,M,P,L]
    const float* __restrict__ nc,     // [B]
    float* __restrict__ out)          // [B,M,P,LE]
{
    __shared__ float sev[L_];
    __shared__ float smu[MSPLIT][L_];
    __shared__ float sal[MSPLIT][L_];
    __shared__ float sbe[MSPLIT][L_];

    const int bid = blockIdx.x;
    const int mc  = bid & (MC - 1);          // m-group (fastest)
    const int row = bid >> 2;                // b*P_ + p
    const int b   = row / P_;
    const int p   = row % P_;
    const int m0  = mc * MSPLIT;
    const int tid = threadIdx.x;             // 0..511

    // ---- issue ev + q loads first
    const float* evrow = ev + (size_t)row * L_;
    const float e0 = (tid < L_) ? evrow[tid] : 0.0f;   // tid<512 always true
    const float4 qv = *(const float4*)(q + (size_t)row * LE_ + 4 * tid);

    // stage sev (ds_write, lgkmcnt-tracked)
    sev[tid] = e0;

    // ---- issue param staging: 6 gload_lds16/thread, vmcnt-tracked
    const size_t pbase   = (((size_t)b * M_ + m0) * P_ + p) * L_;
    const size_t mstride = (size_t)P_ * L_;
    #pragma unroll
    for (int i = 0; i < 2; ++i) {
        const int fidx = tid + 512 * i;          // 0..1023
        const int ml   = fidx >> 7;              // wave-uniform
        const int l4   = (fidx & 127) << 2;      // lane-linear, 16B steps
        const int fb   = (tid & ~63) + 512 * i;  // wave base slot
        const int l4b  = (fb & 127) << 2;
        const size_t g = pbase + (size_t)ml * mstride + l4;
        gload_lds16(mu    + g, &smu[ml][l4b]);
        gload_lds16(alpha + g, &sal[ml][l4b]);
        gload_lds16(beta  + g, &sbe[ml][l4b]);
    }

    // ---- barrier 1: sev visible; params still in flight (no vmcnt drain)
    asm volatile("s_waitcnt lgkmcnt(0)" ::: "memory");
    __builtin_amdgcn_s_barrier();
    __builtin_amdgcn_sched_barrier(0);

    const float ncv    = nc[b];
    const float inv_nc = (float)(1.0 / (double)ncv);  // CR f32 reciprocal

    // ---- search (overlaps param fetch): 4 queries/thread
    int   idx[4];
    float dt[4];
    #pragma unroll
    for (int i = 0; i < 4; ++i) {
        const float qn = ((const float*)&qv)[i] * inv_nc;
        int pos = 0;
        #pragma unroll
        for (int half = 256; half >= 1; half >>= 1) {
            const int cand = pos + half;
            pos = (sev[cand - 1] < qn) ? cand : pos;
        }
        pos += (sev[pos] < qn) ? 1 : 0;      // extend range to 512
        const int last = pos - 1;
        idx[i] = (last < 0) ? 0 : last;
        const float tl = (last < 0) ? 0.0f : sev[idx[i]];
        dt[i] = qn - tl;
    }

    // ---- barrier 2: __syncthreads drains vmcnt(0) -> params in LDS
    __syncthreads();

    // ---- gather + evaluate + store (coalesced float4 per m row)
    const int le0 = 4 * tid;
    const size_t obase = (((size_t)b * M_ + m0) * P_ + p) * LE_ + le0;
    #pragma unroll
    for (int m = 0; m < MSPLIT; ++m) {
        float4 o;
        #pragma unroll
        for (int i = 0; i < 4; ++i) {
            const int   ix  = idx[i];
            const float mul = smu[m][ix];
            const float al  = sal[m][ix];
            const float be  = sbe[m][ix];
            ((float*)&o)[i] = (mul + (al - mul) * __expf(-be * dt[i])) * inv_nc;
        }
        *(float4*)(out + obase + (size_t)m * ((size_t)P_ * LE_)) = o;
    }
}

extern "C" void kernel_launch(void* const* d_in, const int* in_sizes, int n_in,
                              void* d_out, int out_size, void* d_ws, size_t ws_size,
                              hipStream_t stream) {
    const float* q     = (const float*)d_in[0];  // query_times [B,P,LE]
    const float* ev    = (const float*)d_in[1];  // event_times [B,P,L]
    const float* mu    = (const float*)d_in[2];  // [B,M,P,L]
    const float* alpha = (const float*)d_in[3];  // [B,M,P,L]
    const float* beta  = (const float*)d_in[4];  // [B,M,P,L]
    const float* nc    = (const float*)d_in[5];  // [B]
    float* out = (float*)d_out;                  // [B,M,P,LE]

    dim3 grid(B_ * P_ * MC);                     // 2048 blocks
    dim3 block(512);
    hipLaunchKernelGGL(hawkes_intensity_kernel, grid, block, 0, stream,
                       q, ev, mu, alpha, beta, nc, out);
}